// Round 9
// baseline (279.951 us; speedup 1.0000x reference)
//
#include <hip/hip_runtime.h>
#include <math.h>
#include <stdint.h>

namespace {

typedef unsigned short u16;
typedef short    bf16x8 __attribute__((ext_vector_type(8)));   // 8 bf16 (4 VGPR)
typedef float    f32x4  __attribute__((ext_vector_type(4)));
typedef u16      u16x4  __attribute__((ext_vector_type(4)));
typedef u16      u16x8  __attribute__((ext_vector_type(8)));

constexpr int SEQ = 2048;
constexpr int DIM = 1024;
constexpr int NHE = 16;
constexpr int HDM = 64;

__device__ __forceinline__ u16 f2bf(float f) {   // RNE fp32 -> bf16
    uint32_t u = __float_as_uint(f);
    u += 0x7fffu + ((u >> 16) & 1u);
    return (u16)(u >> 16);
}
__device__ __forceinline__ float bf2f(u16 v) {
    return __uint_as_float((uint32_t)v << 16);
}

#define MFMA16(a, b, c) __builtin_amdgcn_mfma_f32_16x16x32_bf16((a), (b), (c), 0, 0, 0)

// async global -> LDS, 16 B per lane (wave-uniform base + lane*16)
__device__ __forceinline__ void gl_lds16(const void* g, void* l) {
    __builtin_amdgcn_global_load_lds(
        (const __attribute__((address_space(1))) void*)g,
        (__attribute__((address_space(3))) void*)l, 16, 0, 0);
}

// ---------------------------------------------------------------------------
// fp32 -> bf16 conversion for x and the 4 weight matrices.
// ---------------------------------------------------------------------------
__global__ __launch_bounds__(256)
void convert_bf16(const float* __restrict__ x,  const float* __restrict__ wq,
                  const float* __restrict__ wk, const float* __restrict__ wv,
                  const float* __restrict__ wo, u16* __restrict__ ws)
{
    const int id = blockIdx.y;
    const float* src;  u16* dst;  int n;
    if      (id == 0) { src = x;  dst = ws;                        n = 1 << 22; }
    else if (id == 1) { src = wq; dst = ws + ((size_t)4 << 20);    n = 1 << 20; }
    else if (id == 2) { src = wk; dst = ws + ((size_t)5 << 20);    n = 1 << 20; }
    else if (id == 3) { src = wv; dst = ws + ((size_t)6 << 20);    n = 1 << 20; }
    else              { src = wo; dst = ws + ((size_t)7 << 20);    n = 1 << 20; }

    const int stride = gridDim.x * 256 * 8;
    for (int i = (blockIdx.x * 256 + threadIdx.x) * 8; i < n; i += stride) {
        const float4 a = *(const float4*)(src + i);
        const float4 b = *(const float4*)(src + i + 4);
        u16x8 o;
        o[0] = f2bf(a.x); o[1] = f2bf(a.y); o[2] = f2bf(a.z); o[3] = f2bf(a.w);
        o[4] = f2bf(b.x); o[5] = f2bf(b.y); o[6] = f2bf(b.z); o[7] = f2bf(b.w);
        *(u16x8*)(dst + i) = o;
    }
}

// ---------------------------------------------------------------------------
// bf16 GEMM core (m97 structure): C[128x128] tile of A[M,1024] @ W[1024,1024]^T.
// ---------------------------------------------------------------------------
__device__ __forceinline__ void gemm_core(
    const u16* __restrict__ A, const u16* __restrict__ W,
    int row0, int col0, u16* As, u16* Bs, f32x4 acc[4][4])
{
    const int tid  = threadIdx.x;
    const int lane = tid & 63;
    const int wave = tid >> 6;
    const int wm = wave >> 1, wn = wave & 1;
    const int col = lane & 15, g = lane >> 4;
    const int qr = lane >> 2, qk = (lane & 3) << 3;

    const u16* Arow0 = A + (size_t)(row0 + wave * 16 + qr) * DIM + qk;
    const u16* Arow1 = A + (size_t)(row0 + 64 + wave * 16 + qr) * DIM + qk;
    const u16* Wrow0 = W + (size_t)(col0 + wave * 16 + qr) * DIM + qk;
    const u16* Wrow1 = W + (size_t)(col0 + 64 + wave * 16 + qr) * DIM + qk;

    u16* lA0 = As + wave * 512 + lane * 8;
    u16* lA1 = As + 2048 + wave * 512 + lane * 8;
    u16* lB0 = Bs + wave * 512 + lane * 8;
    u16* lB1 = Bs + 2048 + wave * 512 + lane * 8;

    for (int kt = 0; kt < DIM; kt += 32) {
        __syncthreads();
        gl_lds16(Arow0 + kt, lA0);
        gl_lds16(Arow1 + kt, lA1);
        gl_lds16(Wrow0 + kt, lB0);
        gl_lds16(Wrow1 + kt, lB1);
        __syncthreads();

        bf16x8 af[4], bfr[4];
        #pragma unroll
        for (int i = 0; i < 4; ++i)
            af[i] = *(const bf16x8*)(As + (wm * 64 + i * 16 + col) * 32 + g * 8);
        #pragma unroll
        for (int i = 0; i < 4; ++i)
            bfr[i] = *(const bf16x8*)(Bs + (wn * 64 + i * 16 + col) * 32 + g * 8);
        #pragma unroll
        for (int i = 0; i < 4; ++i)
            #pragma unroll
            for (int j = 0; j < 4; ++j)
                acc[i][j] = MFMA16(af[i], bfr[j], acc[i][j]);
    }
}

// ---------------------------------------------------------------------------
// QKV projections. z=0 -> Q (PRE-SCALED by 1/sqrt(64)), z=1 -> K (row-major);
// z=2 -> V transposed per head: Vt[(b*16+h)*64 + d][s] (bf16).
// ---------------------------------------------------------------------------
__global__ __launch_bounds__(256)
void gemm_qkv(const u16* __restrict__ xb,  const u16* __restrict__ wqb,
              const u16* __restrict__ wkb, const u16* __restrict__ wvb,
              u16* __restrict__ Qb, u16* __restrict__ Kb, u16* __restrict__ Vtb)
{
    __shared__ u16 As[128 * 32];
    __shared__ u16 Bs[128 * 32];

    const int z = blockIdx.z;
    const u16* W = (z == 0) ? wqb : (z == 1) ? wkb : wvb;
    const int row0 = blockIdx.y * 128, col0 = blockIdx.x * 128;

    f32x4 acc[4][4];
    const f32x4 zero = {0.f, 0.f, 0.f, 0.f};
    #pragma unroll
    for (int i = 0; i < 4; ++i)
        #pragma unroll
        for (int j = 0; j < 4; ++j) acc[i][j] = zero;

    gemm_core(xb, W, row0, col0, As, Bs, acc);

    const int lane = threadIdx.x & 63, wave = threadIdx.x >> 6;
    const int wm = wave >> 1, wn = wave & 1;
    const int col = lane & 15, g = lane >> 4;

    if (z < 2) {
        u16* O = z ? Kb : Qb;
        const float qs = (z == 0) ? 0.125f : 1.0f;   // fold softmax scale into Q
        #pragma unroll
        for (int i = 0; i < 4; ++i) {
            const int r_ = row0 + wm * 64 + i * 16 + g * 4;
            #pragma unroll
            for (int j = 0; j < 4; ++j) {
                const int c_ = col0 + wn * 64 + j * 16 + col;
                #pragma unroll
                for (int r = 0; r < 4; ++r)
                    O[(size_t)(r_ + r) * DIM + c_] = f2bf(acc[i][j][r] * qs);
            }
        }
    } else {
        #pragma unroll
        for (int i = 0; i < 4; ++i) {
            const int r_ = row0 + wm * 64 + i * 16 + g * 4;   // 4-aligned
            const int b = r_ >> 11, s = r_ & 2047;
            #pragma unroll
            for (int j = 0; j < 4; ++j) {
                const int c_ = col0 + wn * 64 + j * 16 + col;
                const int h = c_ >> 6, d = c_ & 63;
                u16x4 pk;
                #pragma unroll
                for (int r = 0; r < 4; ++r) pk[r] = f2bf(acc[i][j][r]);
                *(u16x4*)(Vtb + (((size_t)(b * NHE + h) * HDM + d) << 11) + s) = pk;
            }
        }
    }
}

// ---------------------------------------------------------------------------
// Output projection: out = AO @ wo^T + bias (fp32 out).
// ---------------------------------------------------------------------------
__global__ __launch_bounds__(256)
void gemm_out(const u16* __restrict__ AOb, const u16* __restrict__ wob,
              const float* __restrict__ bias, float* __restrict__ out)
{
    __shared__ u16 As[128 * 32];
    __shared__ u16 Bs[128 * 32];

    const int row0 = blockIdx.y * 128, col0 = blockIdx.x * 128;
    f32x4 acc[4][4];
    const f32x4 zero = {0.f, 0.f, 0.f, 0.f};
    #pragma unroll
    for (int i = 0; i < 4; ++i)
        #pragma unroll
        for (int j = 0; j < 4; ++j) acc[i][j] = zero;

    gemm_core(AOb, wob, row0, col0, As, Bs, acc);

    const int lane = threadIdx.x & 63, wave = threadIdx.x >> 6;
    const int wm = wave >> 1, wn = wave & 1;
    const int col = lane & 15, g = lane >> 4;

    #pragma unroll
    for (int i = 0; i < 4; ++i) {
        const int r_ = row0 + wm * 64 + i * 16 + g * 4;
        #pragma unroll
        for (int j = 0; j < 4; ++j) {
            const int c_ = col0 + wn * 64 + j * 16 + col;
            const float bv = bias[c_];
            #pragma unroll
            for (int r = 0; r < 4; ++r)
                out[(size_t)(r_ + r) * DIM + c_] = acc[i][j][r] + bv;
        }
    }
}

// ---------------------------------------------------------------------------
// MFMA flash attention (causal), block split-K, register-slim for 4 w/SIMD.
// grid = 2048 x 256 thr (4 waves). One q-fragment PAIR (pr, 127-pr) per
// block; 33 k-tiles split across 4 waves; LDS flash merge (as R7).
// R7 lesson: combined VGPR+AGPR ~140 capped residency at 2 waves/SIMD ->
// split-K gained nothing. This round: launch_bounds(256,4) + single K
// buffer + in-place softmax on MFMA regs + Q pre-scaled. Load order
// K -> V -> QK-MFMA keeps V in flight under softmax (counted vmcnt).
// ---------------------------------------------------------------------------
__global__ __launch_bounds__(256, 4)
void attn_mfma(const u16* __restrict__ Qb, const u16* __restrict__ Kb,
               const u16* __restrict__ Vtb, u16* __restrict__ AOb)
{
    __shared__ u16 P[4][16][80];        // 10240 B: [wave][q][key, pad 80]
    __shared__ float Ms[2][4][64];      // 2048 B: [phase][slot][lane]
    __shared__ float Ls[2][4][64];      // 2048 B
    __shared__ u16x4 Os[2][4][4][64];   // 16384 B: bf16 partial O

    const int tid = threadIdx.x, lane = tid & 63, wave = tid >> 6;
    const int col = lane & 15, g = lane >> 4;

    const int lin  = blockIdx.x;                    // 0..2047
    const int wk   = (lin & 7) * 256 + (lin >> 3);  // XCD-contiguous work id
    const int pr   = wk & 63;                       // pair id
    const int head = (wk >> 6) & 15;
    const int b    = wk >> 10;

    const int ntA = (pr >> 2) + 1;      // fragment A tiles; B has 33-ntA

    const u16* Kbase = Kb + (size_t)(b * SEQ) * DIM + head * HDM;
    const u16* Vbase = Vtb + (((size_t)(b * NHE + head) * HDM) << 11);
    const f32x4 zero = {0.f, 0.f, 0.f, 0.f};

    const int lo = (wave * 33) >> 2;          // this wave's global tile range
    const int hi = ((wave + 1) * 33) >> 2;    // 0..8,8..16,16..24,24..33

    #pragma unroll 1
    for (int ph = 0; ph < 2; ++ph) {
        const int f    = ph ? (127 - pr) : pr;
        const int nt   = ph ? (33 - ntA) : ntA;
        const int base = ph ? ntA : 0;
        int tLo = lo - base; if (tLo < 0) tLo = 0;
        int tHi = hi - base; if (tHi > nt) tHi = nt;

        float m = -INFINITY, l = 0.f;
        f32x4 o[4];
        #pragma unroll
        for (int i = 0; i < 4; ++i) o[i] = zero;

        if (tLo < tHi) {
            const int q0 = f * 16;
            const int dt = nt - 1;          // diagonal tile index
            const int qg = q0 + col;
            const u16* Qrow = Qb + (size_t)(b * SEQ + qg) * DIM + head * HDM;
            const bf16x8 qf0 = *(const bf16x8*)(Qrow + g * 8);
            const bf16x8 qf1 = *(const bf16x8*)(Qrow + 32 + g * 8);

            #pragma unroll 1
            for (int kt = tLo; kt < tHi; ++kt) {
                const int k0 = kt * 64;
                // K fragments (needed first)
                bf16x8 kr[8];
                #pragma unroll
                for (int kf = 0; kf < 4; ++kf) {
                    const u16* Krow = Kbase + (size_t)(k0 + kf * 16 + col) * DIM;
                    kr[kf * 2]     = *(const bf16x8*)(Krow + g * 8);
                    kr[kf * 2 + 1] = *(const bf16x8*)(Krow + 32 + g * 8);
                }
                // V fragments: issued now, consumed after softmax (in flight)
                bf16x8 vr[8];
                #pragma unroll
                for (int df = 0; df < 4; ++df) {
                    const u16* Vrow = Vbase + (((size_t)(df * 16 + col)) << 11) + k0;
                    vr[df * 2]     = *(const bf16x8*)(Vrow + g * 8);
                    vr[df * 2 + 1] = *(const bf16x8*)(Vrow + 32 + g * 8);
                }
                // S^T tile (Q pre-scaled, so st = scores directly)
                f32x4 st[4];
                #pragma unroll
                for (int kf = 0; kf < 4; ++kf) {
                    f32x4 z = zero;
                    z = MFMA16(kr[kf * 2], qf0, z);
                    z = MFMA16(kr[kf * 2 + 1], qf1, z);
                    st[kf] = z;
                }

                if (kt == dt) {                  // diagonal: causal mask
                    #pragma unroll
                    for (int kf = 0; kf < 4; ++kf)
                        #pragma unroll
                        for (int r = 0; r < 4; ++r)
                            if (k0 + kf * 16 + g * 4 + r > qg)
                                st[kf][r] = -INFINITY;
                }

                // tree max over 16 in-lane values + cross-group
                float mx[8];
                #pragma unroll
                for (int i = 0; i < 8; ++i)
                    mx[i] = fmaxf(st[i >> 2][i & 3], st[2 + (i >> 2)][i & 3]);
                #pragma unroll
                for (int i = 0; i < 4; ++i) mx[i] = fmaxf(mx[i], mx[i + 4]);
                mx[0] = fmaxf(mx[0], mx[2]); mx[1] = fmaxf(mx[1], mx[3]);
                float mloc = fmaxf(mx[0], mx[1]);
                mloc = fmaxf(mloc, __shfl_xor(mloc, 16));
                mloc = fmaxf(mloc, __shfl_xor(mloc, 32));

                const float mn = fmaxf(m, mloc);
                const float cc = __expf(m - mn);
                #pragma unroll
                for (int kf = 0; kf < 4; ++kf)
                    #pragma unroll
                    for (int r = 0; r < 4; ++r)
                        st[kf][r] = __expf(st[kf][r] - mn);
                float su[8];
                #pragma unroll
                for (int i = 0; i < 8; ++i)
                    su[i] = st[i >> 2][i & 3] + st[2 + (i >> 2)][i & 3];
                #pragma unroll
                for (int i = 0; i < 4; ++i) su[i] = su[i] + su[i + 4];
                float lsum = (su[0] + su[2]) + (su[1] + su[3]);
                lsum += __shfl_xor(lsum, 16);
                lsum += __shfl_xor(lsum, 32);
                l = l * cc + lsum;
                m = mn;

                // P^T -> wave-private LDS (bf16), layout P[q][key]
                #pragma unroll
                for (int kf = 0; kf < 4; ++kf) {
                    u16x4 pk;
                    #pragma unroll
                    for (int r = 0; r < 4; ++r) pk[r] = f2bf(st[kf][r]);
                    *(u16x4*)&P[wave][col][kf * 16 + g * 4] = pk;
                }

                #pragma unroll
                for (int df = 0; df < 4; ++df)
                    #pragma unroll
                    for (int r = 0; r < 4; ++r) o[df][r] *= cc;

                const bf16x8 pb0 = *(const bf16x8*)&P[wave][col][g * 8];
                const bf16x8 pb1 = *(const bf16x8*)&P[wave][col][32 + g * 8];
                #pragma unroll
                for (int df = 0; df < 4; ++df) {
                    o[df] = MFMA16(vr[df * 2],     pb0, o[df]);
                    o[df] = MFMA16(vr[df * 2 + 1], pb1, o[df]);
                }
            }
        }

        // dump partial for this phase (empty partials: m=-inf, l=0, o=0)
        Ms[ph][wave][lane] = m;
        Ls[ph][wave][lane] = l;
        #pragma unroll
        for (int df = 0; df < 4; ++df) {
            u16x4 pk;
            #pragma unroll
            for (int r = 0; r < 4; ++r) pk[r] = f2bf(o[df][r]);
            Os[ph][wave][df][lane] = pk;
        }
    }
    __syncthreads();

    // ---- flash merge (wave 0 -> fragment A, wave 1 -> fragment B) ----
    if (wave < 2) {
        const int ph = wave;
        const int f  = ph ? (127 - pr) : pr;
        float mm[4], ll[4];
        #pragma unroll
        for (int s = 0; s < 4; ++s) { mm[s] = Ms[ph][s][lane]; ll[s] = Ls[ph][s][lane]; }
        const float M = fmaxf(fmaxf(mm[0], mm[1]), fmaxf(mm[2], mm[3]));
        float e[4], L = 0.f;
        #pragma unroll
        for (int s = 0; s < 4; ++s) { e[s] = __expf(mm[s] - M); L += ll[s] * e[s]; }
        const float inv = 1.0f / L;

        const int qg = f * 16 + col;
        u16* Orow = AOb + (size_t)(b * SEQ + qg) * DIM + head * HDM;
        #pragma unroll
        for (int df = 0; df < 4; ++df) {
            const u16x4 p0 = Os[ph][0][df][lane];
            const u16x4 p1 = Os[ph][1][df][lane];
            const u16x4 p2 = Os[ph][2][df][lane];
            const u16x4 p3 = Os[ph][3][df][lane];
            u16x4 pk;
            #pragma unroll
            for (int r = 0; r < 4; ++r) {
                const float v = bf2f(p0[r]) * e[0] + bf2f(p1[r]) * e[1]
                              + bf2f(p2[r]) * e[2] + bf2f(p3[r]) * e[3];
                pk[r] = f2bf(v * inv);
            }
            *(u16x4*)(Orow + df * 16 + g * 4) = pk;
        }
    }
}

} // namespace

// ---------------------------------------------------------------------------
extern "C" void kernel_launch(void* const* d_in, const int* in_sizes, int n_in,
                              void* d_out, int out_size, void* d_ws, size_t ws_size,
                              hipStream_t stream)
{
    const float* x  = (const float*)d_in[0];
    const float* wq = (const float*)d_in[1];
    const float* wk = (const float*)d_in[2];
    const float* wv = (const float*)d_in[3];
    const float* wo = (const float*)d_in[4];
    const float* wb = (const float*)d_in[5];
    float* out = (float*)d_out;

    u16* ws = (u16*)d_ws;                      // 48 MB of bf16 scratch
    u16* xb  = ws;                             // 4M
    u16* wqb = ws + ((size_t)4 << 20);         // 1M each
    u16* wkb = ws + ((size_t)5 << 20);
    u16* wvb = ws + ((size_t)6 << 20);
    u16* wob = ws + ((size_t)7 << 20);
    u16* Qb  = ws + ((size_t)8 << 20);         // 4M
    u16* Kb  = ws + ((size_t)12 << 20);        // 4M
    u16* Vtb = ws + ((size_t)16 << 20);        // 4M
    u16* AOb = ws + ((size_t)20 << 20);        // 4M

    convert_bf16<<<dim3(512, 5), 256, 0, stream>>>(x, wq, wk, wv, wo, ws);
    gemm_qkv<<<dim3(8, 32, 3), 256, 0, stream>>>(xb, wqb, wkb, wvb, Qb, Kb, Vtb);
    attn_mfma<<<2048, 256, 0, stream>>>(Qb, Kb, Vtb, AOb);
    gemm_out<<<dim3(8, 32), 256, 0, stream>>>(AOb, wob, wb, out);
}

// Round 10
// 209.735 us; speedup vs baseline: 1.3348x; 1.3348x over previous
//
#include <hip/hip_runtime.h>
#include <math.h>
#include <stdint.h>

namespace {

typedef unsigned short u16;
typedef short    bf16x8 __attribute__((ext_vector_type(8)));   // 8 bf16 (4 VGPR)
typedef float    f32x4  __attribute__((ext_vector_type(4)));
typedef u16      u16x4  __attribute__((ext_vector_type(4)));
typedef u16      u16x8  __attribute__((ext_vector_type(8)));

constexpr int SEQ = 2048;
constexpr int DIM = 1024;
constexpr int NHE = 16;
constexpr int HDM = 64;

__device__ __forceinline__ u16 f2bf(float f) {   // RNE fp32 -> bf16
    uint32_t u = __float_as_uint(f);
    u += 0x7fffu + ((u >> 16) & 1u);
    return (u16)(u >> 16);
}

#define MFMA16(a, b, c) __builtin_amdgcn_mfma_f32_16x16x32_bf16((a), (b), (c), 0, 0, 0)

// async global -> LDS, 16 B per lane (wave-uniform base + lane*16)
__device__ __forceinline__ void gl_lds16(const void* g, void* l) {
    __builtin_amdgcn_global_load_lds(
        (const __attribute__((address_space(1))) void*)g,
        (__attribute__((address_space(3))) void*)l, 16, 0, 0);
}

// ---------------------------------------------------------------------------
// fp32 -> bf16 conversion for x and the 4 weight matrices.
// ---------------------------------------------------------------------------
__global__ __launch_bounds__(256)
void convert_bf16(const float* __restrict__ x,  const float* __restrict__ wq,
                  const float* __restrict__ wk, const float* __restrict__ wv,
                  const float* __restrict__ wo, u16* __restrict__ ws)
{
    const int id = blockIdx.y;
    const float* src;  u16* dst;  int n;
    if      (id == 0) { src = x;  dst = ws;                        n = 1 << 22; }
    else if (id == 1) { src = wq; dst = ws + ((size_t)4 << 20);    n = 1 << 20; }
    else if (id == 2) { src = wk; dst = ws + ((size_t)5 << 20);    n = 1 << 20; }
    else if (id == 3) { src = wv; dst = ws + ((size_t)6 << 20);    n = 1 << 20; }
    else              { src = wo; dst = ws + ((size_t)7 << 20);    n = 1 << 20; }

    const int stride = gridDim.x * 256 * 8;
    for (int i = (blockIdx.x * 256 + threadIdx.x) * 8; i < n; i += stride) {
        const float4 a = *(const float4*)(src + i);
        const float4 b = *(const float4*)(src + i + 4);
        u16x8 o;
        o[0] = f2bf(a.x); o[1] = f2bf(a.y); o[2] = f2bf(a.z); o[3] = f2bf(a.w);
        o[4] = f2bf(b.x); o[5] = f2bf(b.y); o[6] = f2bf(b.z); o[7] = f2bf(b.w);
        *(u16x8*)(dst + i) = o;
    }
}

// ---------------------------------------------------------------------------
// bf16 GEMM core (m97 structure): C[128x128] tile of A[M,1024] @ W[1024,1024]^T.
// ---------------------------------------------------------------------------
__device__ __forceinline__ void gemm_core(
    const u16* __restrict__ A, const u16* __restrict__ W,
    int row0, int col0, u16* As, u16* Bs, f32x4 acc[4][4])
{
    const int tid  = threadIdx.x;
    const int lane = tid & 63;
    const int wave = tid >> 6;
    const int wm = wave >> 1, wn = wave & 1;
    const int col = lane & 15, g = lane >> 4;
    const int qr = lane >> 2, qk = (lane & 3) << 3;

    const u16* Arow0 = A + (size_t)(row0 + wave * 16 + qr) * DIM + qk;
    const u16* Arow1 = A + (size_t)(row0 + 64 + wave * 16 + qr) * DIM + qk;
    const u16* Wrow0 = W + (size_t)(col0 + wave * 16 + qr) * DIM + qk;
    const u16* Wrow1 = W + (size_t)(col0 + 64 + wave * 16 + qr) * DIM + qk;

    u16* lA0 = As + wave * 512 + lane * 8;
    u16* lA1 = As + 2048 + wave * 512 + lane * 8;
    u16* lB0 = Bs + wave * 512 + lane * 8;
    u16* lB1 = Bs + 2048 + wave * 512 + lane * 8;

    for (int kt = 0; kt < DIM; kt += 32) {
        __syncthreads();
        gl_lds16(Arow0 + kt, lA0);
        gl_lds16(Arow1 + kt, lA1);
        gl_lds16(Wrow0 + kt, lB0);
        gl_lds16(Wrow1 + kt, lB1);
        __syncthreads();

        bf16x8 af[4], bfr[4];
        #pragma unroll
        for (int i = 0; i < 4; ++i)
            af[i] = *(const bf16x8*)(As + (wm * 64 + i * 16 + col) * 32 + g * 8);
        #pragma unroll
        for (int i = 0; i < 4; ++i)
            bfr[i] = *(const bf16x8*)(Bs + (wn * 64 + i * 16 + col) * 32 + g * 8);
        #pragma unroll
        for (int i = 0; i < 4; ++i)
            #pragma unroll
            for (int j = 0; j < 4; ++j)
                acc[i][j] = MFMA16(af[i], bfr[j], acc[i][j]);
    }
}

// ---------------------------------------------------------------------------
// QKV projections. z=0 -> Q (PRE-SCALED by 1/sqrt(64)), z=1 -> K (row-major);
// z=2 -> V transposed per head: Vt[(b*16+h)*64 + d][s] (bf16).
// ---------------------------------------------------------------------------
__global__ __launch_bounds__(256)
void gemm_qkv(const u16* __restrict__ xb,  const u16* __restrict__ wqb,
              const u16* __restrict__ wkb, const u16* __restrict__ wvb,
              u16* __restrict__ Qb, u16* __restrict__ Kb, u16* __restrict__ Vtb)
{
    __shared__ u16 As[128 * 32];
    __shared__ u16 Bs[128 * 32];

    const int z = blockIdx.z;
    const u16* W = (z == 0) ? wqb : (z == 1) ? wkb : wvb;
    const int row0 = blockIdx.y * 128, col0 = blockIdx.x * 128;

    f32x4 acc[4][4];
    const f32x4 zero = {0.f, 0.f, 0.f, 0.f};
    #pragma unroll
    for (int i = 0; i < 4; ++i)
        #pragma unroll
        for (int j = 0; j < 4; ++j) acc[i][j] = zero;

    gemm_core(xb, W, row0, col0, As, Bs, acc);

    const int lane = threadIdx.x & 63, wave = threadIdx.x >> 6;
    const int wm = wave >> 1, wn = wave & 1;
    const int col = lane & 15, g = lane >> 4;

    if (z < 2) {
        u16* O = z ? Kb : Qb;
        const float qs = (z == 0) ? 0.125f : 1.0f;   // fold softmax scale into Q
        #pragma unroll
        for (int i = 0; i < 4; ++i) {
            const int r_ = row0 + wm * 64 + i * 16 + g * 4;
            #pragma unroll
            for (int j = 0; j < 4; ++j) {
                const int c_ = col0 + wn * 64 + j * 16 + col;
                #pragma unroll
                for (int r = 0; r < 4; ++r)
                    O[(size_t)(r_ + r) * DIM + c_] = f2bf(acc[i][j][r] * qs);
            }
        }
    } else {
        #pragma unroll
        for (int i = 0; i < 4; ++i) {
            const int r_ = row0 + wm * 64 + i * 16 + g * 4;   // 4-aligned
            const int b = r_ >> 11, s = r_ & 2047;
            #pragma unroll
            for (int j = 0; j < 4; ++j) {
                const int c_ = col0 + wn * 64 + j * 16 + col;
                const int h = c_ >> 6, d = c_ & 63;
                u16x4 pk;
                #pragma unroll
                for (int r = 0; r < 4; ++r) pk[r] = f2bf(acc[i][j][r]);
                *(u16x4*)(Vtb + (((size_t)(b * NHE + h) * HDM + d) << 11) + s) = pk;
            }
        }
    }
}

// ---------------------------------------------------------------------------
// Output projection: out = AO @ wo^T + bias (fp32 out).
// ---------------------------------------------------------------------------
__global__ __launch_bounds__(256)
void gemm_out(const u16* __restrict__ AOb, const u16* __restrict__ wob,
              const float* __restrict__ bias, float* __restrict__ out)
{
    __shared__ u16 As[128 * 32];
    __shared__ u16 Bs[128 * 32];

    const int row0 = blockIdx.y * 128, col0 = blockIdx.x * 128;
    f32x4 acc[4][4];
    const f32x4 zero = {0.f, 0.f, 0.f, 0.f};
    #pragma unroll
    for (int i = 0; i < 4; ++i)
        #pragma unroll
        for (int j = 0; j < 4; ++j) acc[i][j] = zero;

    gemm_core(AOb, wob, row0, col0, As, Bs, acc);

    const int lane = threadIdx.x & 63, wave = threadIdx.x >> 6;
    const int wm = wave >> 1, wn = wave & 1;
    const int col = lane & 15, g = lane >> 4;

    #pragma unroll
    for (int i = 0; i < 4; ++i) {
        const int r_ = row0 + wm * 64 + i * 16 + g * 4;
        #pragma unroll
        for (int j = 0; j < 4; ++j) {
            const int c_ = col0 + wn * 64 + j * 16 + col;
            const float bv = bias[c_];
            #pragma unroll
            for (int r = 0; r < 4; ++r)
                out[(size_t)(r_ + r) * DIM + c_] = acc[i][j][r] + bv;
        }
    }
}

// ---------------------------------------------------------------------------
// MFMA flash attention (causal), LDS-staged K/V shared by 4 waves.
// grid = 512 x 256 thr. Block owns balanced q-tile pair (T, 31-T): 64 rows
// per phase, wave w handles rows +16w..+16w+15; 33 k-tiles total per block.
// K/V tiles staged cooperatively via global_load_lds (contiguous 128B rows,
// double-buffered) with XOR swizzle byte^=(row&7)<<4 applied on the GLOBAL
// source (linear LDS dest) and on ds_read addrs -> conflict-free b128 reads.
// R9 lesson: per-wave scattered K/V reg loads saturated the vmem address
// path (~1160 cyc/CU/tile-iter, occupancy-insensitive). This cuts vmem
// instructions 4x (shared tiles) and makes every segment contiguous.
// ---------------------------------------------------------------------------
__global__ __launch_bounds__(256, 2)
void attn_mfma(const u16* __restrict__ Qb, const u16* __restrict__ Kb,
               const u16* __restrict__ Vtb, u16* __restrict__ AOb)
{
    __shared__ u16 Kl[2][64 * 64];      // 16 KB: [buf][row*64 + d] (swizzled)
    __shared__ u16 Vl[2][64 * 64];      // 16 KB: [buf][d-row*64 + s]
    __shared__ u16 P[4][16][80];        // 10 KB: [wave][q][key, pad 80]

    const int tid = threadIdx.x, lane = tid & 63, wave = tid >> 6;
    const int col = lane & 15, g = lane >> 4;

    const int lin  = blockIdx.x;                  // 0..511
    const int wk   = (lin & 7) * 64 + (lin >> 3); // XCD-contiguous work id
    const int T    = wk & 15;                     // pair (T, 31-T)
    const int head = (wk >> 4) & 15;
    const int b    = wk >> 8;

    const u16* Kbase = Kb + (size_t)(b * SEQ) * DIM + head * HDM;
    const u16* Vbase = Vtb + (((size_t)(b * NHE + head) * HDM) << 11);
    const f32x4 zero = {0.f, 0.f, 0.f, 0.f};

    // Q fragments for both phases (Q pre-scaled by 0.125 in projection)
    const int qgA = T * 64 + wave * 16 + col;
    const int qgB = (31 - T) * 64 + wave * 16 + col;
    const u16* QrowA = Qb + (size_t)(b * SEQ + qgA) * DIM + head * HDM;
    const u16* QrowB = Qb + (size_t)(b * SEQ + qgB) * DIM + head * HDM;
    const bf16x8 qA0 = *(const bf16x8*)(QrowA + g * 8);
    const bf16x8 qA1 = *(const bf16x8*)(QrowA + 32 + g * 8);
    const bf16x8 qB0 = *(const bf16x8*)(QrowB + g * 8);
    const bf16x8 qB1 = *(const bf16x8*)(QrowB + 32 + g * 8);

    // staging: waves 0,1 -> K rows 0..31 / 32..63; waves 2,3 -> V ditto.
    const bool isK = wave < 2;
    const int  r0  = (wave & 1) * 32;

    auto stage = [&](int flat) {
        const int kt  = (flat > T) ? flat - T - 1 : flat;
        const int k0  = kt * 64;
        const int buf = flat & 1;
        u16* lb = (isK ? &Kl[buf][0] : &Vl[buf][0]);
        #pragma unroll
        for (int j = 0; j < 4; ++j) {
            const int row  = r0 + j * 8 + (lane >> 3);
            const int colb = (lane & 7) * 16;                    // byte col
            const int scol = (colb ^ ((row & 7) << 4)) >> 1;     // swizzled, u16
            const u16* gsrc = isK
                ? (Kbase + (size_t)(k0 + row) * DIM + scol)      // key row
                : (Vbase + ((size_t)row << 11) + k0 + scol);     // d row
            gl_lds16(gsrc, lb + row * 64 + (lane & 7) * 8);      // linear dest
        }
    };

    float m = -INFINITY, l = 0.f;
    f32x4 o[4];
    #pragma unroll
    for (int i = 0; i < 4; ++i) o[i] = zero;

    stage(0);
    __syncthreads();                      // drain staging (vmcnt0) + join

    #pragma unroll 1
    for (int flat = 0; flat <= 32; ++flat) {
        if (flat < 32) stage(flat + 1);   // prefetch into other buffer

        const bool phB = flat > T;
        const int kt  = phB ? flat - T - 1 : flat;
        const int k0  = kt * 64;
        const int buf = flat & 1;
        const int qg  = phB ? qgB : qgA;
        const bf16x8 qf0 = phB ? qB0 : qA0;
        const bf16x8 qf1 = phB ? qB1 : qA1;
        const bool diag = (flat == T) || (flat == 32);

        // S^T tile: K fragments from swizzled LDS
        f32x4 st[4];
        #pragma unroll
        for (int kf = 0; kf < 4; ++kf) {
            const int row = kf * 16 + col;
            const int swz = (row & 7) << 4;
            const bf16x8 ka0 = *(const bf16x8*)(&Kl[buf][0] + row * 64 + (((g * 16) ^ swz) >> 1));
            const bf16x8 ka1 = *(const bf16x8*)(&Kl[buf][0] + row * 64 + (((64 + g * 16) ^ swz) >> 1));
            f32x4 z = zero;
            z = MFMA16(ka0, qf0, z);
            z = MFMA16(ka1, qf1, z);
            st[kf] = z;
        }

        if (diag) {                       // causal mask on diagonal tile
            #pragma unroll
            for (int kf = 0; kf < 4; ++kf)
                #pragma unroll
                for (int r = 0; r < 4; ++r)
                    if (k0 + kf * 16 + g * 4 + r > qg)
                        st[kf][r] = -INFINITY;
        }

        // tree max over 16 in-lane values + cross-group
        float mx[8];
        #pragma unroll
        for (int i = 0; i < 8; ++i)
            mx[i] = fmaxf(st[i >> 2][i & 3], st[2 + (i >> 2)][i & 3]);
        #pragma unroll
        for (int i = 0; i < 4; ++i) mx[i] = fmaxf(mx[i], mx[i + 4]);
        mx[0] = fmaxf(mx[0], mx[2]); mx[1] = fmaxf(mx[1], mx[3]);
        float mloc = fmaxf(mx[0], mx[1]);
        mloc = fmaxf(mloc, __shfl_xor(mloc, 16));
        mloc = fmaxf(mloc, __shfl_xor(mloc, 32));

        const float mn = fmaxf(m, mloc);
        const float cc = __expf(m - mn);
        #pragma unroll
        for (int kf = 0; kf < 4; ++kf)
            #pragma unroll
            for (int r = 0; r < 4; ++r)
                st[kf][r] = __expf(st[kf][r] - mn);
        float su[8];
        #pragma unroll
        for (int i = 0; i < 8; ++i)
            su[i] = st[i >> 2][i & 3] + st[2 + (i >> 2)][i & 3];
        #pragma unroll
        for (int i = 0; i < 4; ++i) su[i] = su[i] + su[i + 4];
        float lsum = (su[0] + su[2]) + (su[1] + su[3]);
        lsum += __shfl_xor(lsum, 16);
        lsum += __shfl_xor(lsum, 32);
        l = l * cc + lsum;
        m = mn;

        // P^T -> wave-private LDS (bf16), layout P[q][key]
        #pragma unroll
        for (int kf = 0; kf < 4; ++kf) {
            u16x4 pk;
            #pragma unroll
            for (int r = 0; r < 4; ++r) pk[r] = f2bf(st[kf][r]);
            *(u16x4*)&P[wave][col][kf * 16 + g * 4] = pk;
        }

        #pragma unroll
        for (int df = 0; df < 4; ++df)
            #pragma unroll
            for (int r = 0; r < 4; ++r) o[df][r] *= cc;

        const bf16x8 pb0 = *(const bf16x8*)&P[wave][col][g * 8];
        const bf16x8 pb1 = *(const bf16x8*)&P[wave][col][32 + g * 8];
        #pragma unroll
        for (int df = 0; df < 4; ++df) {
            const int row = df * 16 + col;
            const int swz = (row & 7) << 4;
            const bf16x8 va0 = *(const bf16x8*)(&Vl[buf][0] + row * 64 + (((g * 16) ^ swz) >> 1));
            const bf16x8 va1 = *(const bf16x8*)(&Vl[buf][0] + row * 64 + (((64 + g * 16) ^ swz) >> 1));
            o[df] = MFMA16(va0, pb0, o[df]);
            o[df] = MFMA16(va1, pb1, o[df]);
        }

        if (flat == T) {                  // phase A complete: store + reset
            const float invl = 1.0f / l;
            u16* Orow = AOb + (size_t)(b * SEQ + qgA) * DIM + head * HDM;
            #pragma unroll
            for (int df = 0; df < 4; ++df) {
                u16x4 pk;
                #pragma unroll
                for (int r = 0; r < 4; ++r) pk[r] = f2bf(o[df][r] * invl);
                *(u16x4*)(Orow + df * 16 + g * 4) = pk;
            }
            m = -INFINITY; l = 0.f;
            #pragma unroll
            for (int i = 0; i < 4; ++i) o[i] = zero;
        }

        __syncthreads();                  // staged tile ready; all reads done
    }

    // phase B output
    const float invl = 1.0f / l;
    u16* Orow = AOb + (size_t)(b * SEQ + qgB) * DIM + head * HDM;
    #pragma unroll
    for (int df = 0; df < 4; ++df) {
        u16x4 pk;
        #pragma unroll
        for (int r = 0; r < 4; ++r) pk[r] = f2bf(o[df][r] * invl);
        *(u16x4*)(Orow + df * 16 + g * 4) = pk;
    }
}

} // namespace

// ---------------------------------------------------------------------------
extern "C" void kernel_launch(void* const* d_in, const int* in_sizes, int n_in,
                              void* d_out, int out_size, void* d_ws, size_t ws_size,
                              hipStream_t stream)
{
    const float* x  = (const float*)d_in[0];
    const float* wq = (const float*)d_in[1];
    const float* wk = (const float*)d_in[2];
    const float* wv = (const float*)d_in[3];
    const float* wo = (const float*)d_in[4];
    const float* wb = (const float*)d_in[5];
    float* out = (float*)d_out;

    u16* ws = (u16*)d_ws;                      // 48 MB of bf16 scratch
    u16* xb  = ws;                             // 4M
    u16* wqb = ws + ((size_t)4 << 20);         // 1M each
    u16* wkb = ws + ((size_t)5 << 20);
    u16* wvb = ws + ((size_t)6 << 20);
    u16* wob = ws + ((size_t)7 << 20);
    u16* Qb  = ws + ((size_t)8 << 20);         // 4M
    u16* Kb  = ws + ((size_t)12 << 20);        // 4M
    u16* Vtb = ws + ((size_t)16 << 20);        // 4M
    u16* AOb = ws + ((size_t)20 << 20);        // 4M

    convert_bf16<<<dim3(512, 5), 256, 0, stream>>>(x, wq, wk, wv, wo, ws);
    gemm_qkv<<<dim3(8, 32, 3), 256, 0, stream>>>(xb, wqb, wkb, wvb, Qb, Kb, Vtb);
    attn_mfma<<<512, 256, 0, stream>>>(Qb, Kb, Vtb, AOb);
    gemm_out<<<dim3(8, 32), 256, 0, stream>>>(AOb, wob, wb, out);
}